// Round 5
// baseline (832.134 us; speedup 1.0000x reference)
//
#include <hip/hip_runtime.h>
#include <hip/hip_bf16.h>
#include <stdint.h>

#define B_    2048
#define F_    12800
#define DLLM_ 768
#define E_    8
#define HK_   13568            // gate virtual K (768 dkp + 12800 xf)
#define A2S_  27136            // A2 row stride = 2*HK_ (hi | lo)
#define G1KC  3392             // gate1 per-split K range (27136/8)
#define MKSPLIT 8
#define MKPER (F_ / MKSPLIT)   // 1600
#define BK    64

typedef __bf16 bf16x8 __attribute__((ext_vector_type(8)));
typedef float  f32x4  __attribute__((ext_vector_type(4)));

__device__ __forceinline__ unsigned short f2bf(float f) {
    unsigned int u = __float_as_uint(f);
    u += 0x7fffu + ((u >> 16) & 1u);           // RNE
    return (unsigned short)(u >> 16);
}
__device__ __forceinline__ float bf2f(unsigned short u) {
    return __uint_as_float(((unsigned int)u) << 16);
}

// -------- build A2 [2048][27136] = [hi(dkp)|hi(xf)|lo(dkp)|lo(xf)] bf16 --------
__global__ __launch_bounds__(256) void k_build_a2(const float* __restrict__ dkp,
                                                  const float* __restrict__ ccd,
                                                  unsigned short* __restrict__ A2) {
    int i = blockIdx.x * 256 + threadIdx.x;     // over 2048*3392 float4 groups
    int row = i / 3392;
    int c = (i - row * 3392) * 4;               // gate col 0..13564
    const float* src = (c < DLLM_) ? dkp + (size_t)row * DLLM_ + c
                                   : ccd + (size_t)row * F_ + (c - DLLM_);
    float4 v = *(const float4*)src;
    ushort4 h, l;
    h.x = f2bf(v.x); l.x = f2bf(v.x - bf2f(h.x));
    h.y = f2bf(v.y); l.y = f2bf(v.y - bf2f(h.y));
    h.z = f2bf(v.z); l.z = f2bf(v.z - bf2f(h.z));
    h.w = f2bf(v.w); l.w = f2bf(v.w - bf2f(h.w));
    *(ushort4*)&A2[(size_t)row * A2S_ + c] = h;
    *(ushort4*)&A2[(size_t)row * A2S_ + HK_ + c] = l;
}

// ---------------- fp32 -> bf16 flat convert (fallback modes only) ----------------
__global__ __launch_bounds__(256) void k_convert(const float* __restrict__ src,
                                                 unsigned short* __restrict__ dst, int n4) {
    int i = blockIdx.x * 256 + threadIdx.x;
    if (i >= n4) return;
    float4 v = ((const float4*)src)[i];
    ushort4 o;
    o.x = f2bf(v.x); o.y = f2bf(v.y); o.z = f2bf(v.z); o.w = f2bf(v.w);
    ((ushort4*)dst)[i] = o;
}

// ------------- transpose+convert We [e][K][128] -> WeT [e][128][K], Wgen likewise -------------
__global__ __launch_bounds__(256) void k_transpose_bf16(const float* __restrict__ We,
                                                        const float* __restrict__ Wgen,
                                                        unsigned short* __restrict__ WeT,
                                                        unsigned short* __restrict__ WgenT) {
    __shared__ float t[32][33];
    int z = blockIdx.z;
    const float* src = (z < 8) ? (We + (size_t)z * F_ * 128) : Wgen;
    unsigned short* dst = (z < 8) ? (WeT + (size_t)z * 128 * F_) : WgenT;
    int k0 = blockIdx.x * 32, n0 = blockIdx.y * 32;
    int tx = threadIdx.x, ty = threadIdx.y;  // 32 x 8
#pragma unroll
    for (int i = 0; i < 4; i++) {
        int k = k0 + ty + i * 8;
        t[ty + i * 8][tx] = src[(size_t)k * 128 + n0 + tx];
    }
    __syncthreads();
#pragma unroll
    for (int i = 0; i < 4; i++) {
        int n = n0 + ty + i * 8;
        dst[(size_t)n * F_ + k0 + tx] = f2bf(t[tx][ty + i * 8]);
    }
}

// ------- build BgT [2][256][27136]: v0 = [hi(Wg1)|lo(Wg1)], v1 = [lo|hi], transposed -------
__global__ __launch_bounds__(256) void k_build_bgt(const float* __restrict__ Wg1,
                                                   unsigned short* __restrict__ BgT) {
    __shared__ float t[32][33];
    int k0 = blockIdx.x * 32, n0 = blockIdx.y * 32;
    int tx = threadIdx.x, ty = threadIdx.y;  // 32 x 8
#pragma unroll
    for (int i = 0; i < 4; i++) {
        int g = k0 + ty + i * 8;
        int wr = g + (g >= DLLM_ ? 1 : 0);   // skip virtual cycle row 768
        t[ty + i * 8][tx] = Wg1[(size_t)wr * 256 + n0 + tx];
    }
    __syncthreads();
#pragma unroll
    for (int i = 0; i < 4; i++) {
        int n = n0 + ty + i * 8;
        int g = k0 + tx;
        float v = t[tx][ty + i * 8];
        unsigned short h = f2bf(v);
        unsigned short l = f2bf(v - bf2f(h));
        BgT[(size_t)n * A2S_ + g]              = h;
        BgT[(size_t)n * A2S_ + HK_ + g]        = l;
        BgT[(size_t)(256 + n) * A2S_ + g]       = l;
        BgT[(size_t)(256 + n) * A2S_ + HK_ + g] = h;
    }
}

// -------- gate layer-1 via bf16 MFMA: h_part[z] = A2-chunk @ BgT[v]-chunk --------
// 64x256 tile, BK=64, 16x16x32 MFMA; z in [0,16): variant = z>>3, k-range (z&7)*3392.
__global__ __launch_bounds__(256) void k_gate1_mfma(const unsigned short* __restrict__ A2,
                                                    const unsigned short* __restrict__ BgT,
                                                    float* __restrict__ h_part) {
    __shared__ unsigned short As[64 * 72];
    __shared__ unsigned short Bs[256 * 72];
    int m0 = blockIdx.x * 64;
    int z = blockIdx.y;
    int v = z >> 3;
    int k0 = (z & 7) * G1KC;
    int t = threadIdx.x;

    int arow = t >> 2, akq = t & 3;
    const unsigned short* aptr = A2 + (size_t)(m0 + arow) * A2S_ + k0 + akq * 8;
    unsigned short* asd0 = &As[arow * 72 + akq * 8];
    unsigned short* asd1 = &As[arow * 72 + (akq + 4) * 8];
    const unsigned short* bptr = BgT + (size_t)(v * 256 + t) * A2S_ + k0;
    unsigned short* bsd = &Bs[t * 72];

    int lane = t & 63, lm = lane & 15, lg = lane >> 4;
    int w = t >> 6;                 // wave covers cols w*64..w*64+63

    f32x4 acc[4][4];
#pragma unroll
    for (int i = 0; i < 4; i++)
#pragma unroll
        for (int j = 0; j < 4; j++) acc[i][j] = (f32x4){0.f, 0.f, 0.f, 0.f};

    uint4 ra0 = *(const uint4*)aptr;
    uint4 ra1 = *(const uint4*)(aptr + 32);
    uint4 rb[8];
#pragma unroll
    for (int j = 0; j < 8; j++) rb[j] = *(const uint4*)(bptr + j * 8);

    for (int kk = 0; kk < G1KC; kk += BK) {
        __syncthreads();
        *(uint4*)asd0 = ra0;
        *(uint4*)asd1 = ra1;
#pragma unroll
        for (int j = 0; j < 8; j++) *(uint4*)(bsd + j * 8) = rb[j];
        __syncthreads();
        if (kk + BK < G1KC) {
            aptr += BK; bptr += BK;
            ra0 = *(const uint4*)aptr;
            ra1 = *(const uint4*)(aptr + 32);
#pragma unroll
            for (int j = 0; j < 8; j++) rb[j] = *(const uint4*)(bptr + j * 8);
        }
#pragma unroll
        for (int kb = 0; kb < 2; kb++) {
            bf16x8 af[4], bf[4];
#pragma unroll
            for (int mt = 0; mt < 4; mt++)
                af[mt] = *(const bf16x8*)&As[(mt * 16 + lm) * 72 + (kb * 4 + lg) * 8];
#pragma unroll
            for (int nt = 0; nt < 4; nt++)
                bf[nt] = *(const bf16x8*)&Bs[(w * 64 + nt * 16 + lm) * 72 + (kb * 4 + lg) * 8];
#pragma unroll
            for (int mt = 0; mt < 4; mt++)
#pragma unroll
                for (int nt = 0; nt < 4; nt++)
                    acc[mt][nt] = __builtin_amdgcn_mfma_f32_16x16x32_bf16(af[mt], bf[nt], acc[mt][nt], 0, 0, 0);
        }
    }
    float* dst = h_part + (size_t)z * B_ * 256;
#pragma unroll
    for (int mt = 0; mt < 4; mt++) {
#pragma unroll
        for (int nt = 0; nt < 4; nt++) {
            int col = w * 64 + nt * 16 + lm;
#pragma unroll
            for (int r = 0; r < 4; r++) {
                int row = m0 + mt * 16 + lg * 4 + r;
                dst[(size_t)row * 256 + col] = acc[mt][nt][r];
            }
        }
    }
}

// -------- fallback gate layer-1 (fp32 vector), z=16 even chunks of 53 iters --------
__global__ __launch_bounds__(256, 2) void k_gate1_f32(const float* __restrict__ dkp,
                                                      const float* __restrict__ xf,
                                                      const float* __restrict__ Wg1,
                                                      float* __restrict__ h_part,
                                                      int nparts) {
    __shared__ float As[16][132];
    __shared__ float Bs[16][260];
    int m0 = blockIdx.x * 128;
    int s = blockIdx.y;
    int kbeg = s * 848, kend = kbeg + 848;
    int t = threadIdx.x;
    int tm = t >> 5, tn = t & 31;

    float acc[16][8];
#pragma unroll
    for (int i = 0; i < 16; i++)
#pragma unroll
        for (int j = 0; j < 8; j++) acc[i][j] = 0.f;

    int arow = t >> 2, akq = (t & 3) * 4;
    int bkr = t >> 6, bcol = (t & 63) * 4;

    float4 aR[2], bR[4];
    auto preload = [&](int k) {
        const float* Ab; int astr, aoff, wr0;
        if (k < DLLM_) { Ab = dkp; astr = DLLM_; aoff = k; wr0 = k; }
        else           { Ab = xf;  astr = F_;    aoff = k - DLLM_; wr0 = k + 1; }
        aR[0] = *(const float4*)&Ab[(size_t)(m0 + arow) * astr + aoff + akq];
        aR[1] = *(const float4*)&Ab[(size_t)(m0 + arow + 64) * astr + aoff + akq];
#pragma unroll
        for (int r = 0; r < 4; r++)
            bR[r] = *(const float4*)&Wg1[(size_t)(wr0 + bkr + r * 4) * 256 + bcol];
    };
    preload(kbeg);
    for (int k = kbeg; k < kend; k += 16) {
        __syncthreads();
        {
            float a0[4] = {aR[0].x, aR[0].y, aR[0].z, aR[0].w};
            float a1[4] = {aR[1].x, aR[1].y, aR[1].z, aR[1].w};
#pragma unroll
            for (int j = 0; j < 4; j++) {
                As[akq + j][arow]      = a0[j];
                As[akq + j][arow + 64] = a1[j];
            }
#pragma unroll
            for (int r = 0; r < 4; r++)
                *(float4*)&Bs[bkr + r * 4][bcol] = bR[r];
        }
        __syncthreads();
        if (k + 16 < kend) preload(k + 16);
#pragma unroll 4
        for (int kk = 0; kk < 16; kk++) {
            float4 a0 = *(const float4*)&As[kk][tm * 16];
            float4 a1 = *(const float4*)&As[kk][tm * 16 + 4];
            float4 a2 = *(const float4*)&As[kk][tm * 16 + 8];
            float4 a3 = *(const float4*)&As[kk][tm * 16 + 12];
            float4 b0 = *(const float4*)&Bs[kk][tn * 4];
            float4 b1 = *(const float4*)&Bs[kk][128 + tn * 4];
            float av[16] = {a0.x, a0.y, a0.z, a0.w, a1.x, a1.y, a1.z, a1.w,
                            a2.x, a2.y, a2.z, a2.w, a3.x, a3.y, a3.z, a3.w};
            float bv[8]  = {b0.x, b0.y, b0.z, b0.w, b1.x, b1.y, b1.z, b1.w};
#pragma unroll
            for (int i = 0; i < 16; i++)
#pragma unroll
                for (int j = 0; j < 8; j++) acc[i][j] = fmaf(av[i], bv[j], acc[i][j]);
        }
    }
    if (nparts > 1) {
        float* dst = h_part + (size_t)s * B_ * 256;
#pragma unroll
        for (int i = 0; i < 16; i++) {
            size_t base = (size_t)(m0 + tm * 16 + i) * 256;
            *(float4*)&dst[base + tn * 4]       = (float4){acc[i][0], acc[i][1], acc[i][2], acc[i][3]};
            *(float4*)&dst[base + 128 + tn * 4] = (float4){acc[i][4], acc[i][5], acc[i][6], acc[i][7]};
        }
    } else {
#pragma unroll
        for (int i = 0; i < 16; i++) {
            size_t base = (size_t)(m0 + tm * 16 + i) * 256;
#pragma unroll
            for (int j = 0; j < 4; j++) atomicAdd(&h_part[base + tn * 4 + j], acc[i][j]);
#pragma unroll
            for (int j = 4; j < 8; j++) atomicAdd(&h_part[base + 128 + tn * 4 + j - 4], acc[i][j]);
        }
    }
}

// ---------------- gate layer-2: reduce partials, gelu, logits, top-2, gates, row lists ----------------
__global__ __launch_bounds__(256) void k_gate2(const float* __restrict__ h_part,
                                               const float* __restrict__ cyc,
                                               const float* __restrict__ Wg1,
                                               const float* __restrict__ bg1,
                                               const float* __restrict__ Wg2,
                                               const float* __restrict__ bg2,
                                               float* __restrict__ gates,
                                               unsigned int* __restrict__ cnt,
                                               unsigned int* __restrict__ rows,
                                               int nparts) {
    __shared__ float hs[8 * 257];
    __shared__ float w2s[256 * 8];
    __shared__ float ls[8][9];
    int r0 = blockIdx.x * 8;
    int t = threadIdx.x;
    const float* w768 = Wg1 + (size_t)DLLM_ * 256;
    float wc = w768[t], b1c = bg1[t];
#pragma unroll
    for (int i = 0; i < 8; i++) {
        size_t idx = (size_t)(r0 + i) * 256 + t;
        float x = 0.f;
        for (int p = 0; p < nparts; p++) x += h_part[(size_t)p * B_ * 256 + idx];
        x += cyc[r0 + i] * wc + b1c;
        float x3 = x * x * x;
        float g = 0.5f * x * (1.f + tanhf(0.7978845608028654f * (x + 0.044715f * x3)));
        hs[i * 257 + t] = g;
    }
#pragma unroll
    for (int i = 0; i < 8; i++) w2s[i * 256 + t] = Wg2[i * 256 + t];
    __syncthreads();
    if (t < 64) {
        int r = t >> 3, e = t & 7;
        float s = bg2[e];
        for (int k2 = 0; k2 < 256; k2++) s = fmaf(hs[r * 257 + k2], w2s[k2 * 8 + e], s);
        ls[r][e] = s;
    }
    __syncthreads();
    if (t < 8) {
        float l[8];
#pragma unroll
        for (int e = 0; e < 8; e++) l[e] = ls[t][e];
        int i1 = 0; float v1 = l[0];
#pragma unroll
        for (int e = 1; e < 8; e++) if (l[e] > v1) { v1 = l[e]; i1 = e; }
        int i2 = -1; float v2 = -3.0e38f;
#pragma unroll
        for (int e = 0; e < 8; e++) if (e != i1 && l[e] > v2) { v2 = l[e]; i2 = e; }
        float p[8], ps = 0.f;
#pragma unroll
        for (int e = 0; e < 8; e++) { p[e] = expf(l[e] - v1); ps += p[e]; }
        float msum = (p[i1] + p[i2]) / ps;
        float gi = 1.f / (msum + 1e-9f);
        int row = r0 + t;
#pragma unroll
        for (int e = 0; e < 8; e++) {
            float ge = (e == i1 || e == i2) ? (p[e] / ps) * gi : 0.f;
            gates[row * 8 + e] = ge;
        }
        unsigned int s1 = atomicAdd(&cnt[i1], 1u); rows[i1 * 2048 + s1] = (unsigned int)row;
        unsigned int s2 = atomicAdd(&cnt[i2], 1u); rows[i2 * 2048 + s2] = (unsigned int)row | 0x10000u;
    }
}

// ------- grouped expert GEMM + general GEMM (bf16 MFMA 16x16x32, BK=64) -------
__global__ __launch_bounds__(256) void k_moe(const unsigned short* __restrict__ xrows,
                                             int astride,
                                             const unsigned short* __restrict__ WeT,
                                             const unsigned short* __restrict__ WgenT,
                                             const float* __restrict__ be,
                                             const float* __restrict__ gates,
                                             const unsigned int* __restrict__ cnt,
                                             const unsigned int* __restrict__ rows,
                                             float* __restrict__ comb_part,
                                             float* __restrict__ gen_part,
                                             int pflag) {
    __shared__ unsigned short As[64 * 72];
    __shared__ unsigned short Bs[128 * 72];
    __shared__ unsigned int rowid_s[64];
    int e = blockIdx.y, tile = blockIdx.x, split = blockIdx.z;
    int n_rows = (e < 8) ? (int)cnt[e] : 2048;
    if (tile * 64 >= n_rows) return;
    int t = threadIdx.x;
    if (t < 64) {
        int m = tile * 64 + t;
        unsigned int entry = (e < 8) ? ((m < n_rows) ? rows[e * 2048 + m] : rows[e * 2048])
                                     : (unsigned int)m;
        rowid_s[t] = entry;
    }
    __syncthreads();
    const unsigned short* WT = (e < 8) ? (WeT + (size_t)e * 128 * F_) : WgenT;
    int k0 = split * MKPER;

    int arow = t >> 2, akq = t & 3;
    const unsigned short* aptr = xrows + (size_t)(rowid_s[arow] & 0xFFFFu) * astride + k0 + akq * 8;
    unsigned short* asd0 = &As[arow * 72 + akq * 8];
    unsigned short* asd1 = &As[arow * 72 + (akq + 4) * 8];
    int bcol = t >> 1, bh = t & 1;
    const unsigned short* bptr = WT + (size_t)bcol * F_ + k0 + bh * 32;
    unsigned short* bsd = &Bs[bcol * 72 + bh * 32];

    int lane = t & 63;
    int lm = lane & 15, lg = lane >> 4;
    int wave = t >> 6, wr = wave >> 1, wc2 = wave & 1;

    f32x4 acc[2][4];
#pragma unroll
    for (int i = 0; i < 2; i++)
#pragma unroll
        for (int j = 0; j < 4; j++) acc[i][j] = (f32x4){0.f, 0.f, 0.f, 0.f};

    uint4 ra0 = *(const uint4*)aptr;
    uint4 ra1 = *(const uint4*)(aptr + 32);
    uint4 rb0 = *(const uint4*)(bptr);
    uint4 rb1 = *(const uint4*)(bptr + 8);
    uint4 rb2 = *(const uint4*)(bptr + 16);
    uint4 rb3 = *(const uint4*)(bptr + 24);
    for (int kk = 0; kk < MKPER; kk += BK) {
        __syncthreads();
        *(uint4*)asd0 = ra0;
        *(uint4*)asd1 = ra1;
        *(uint4*)(bsd)      = rb0;
        *(uint4*)(bsd + 8)  = rb1;
        *(uint4*)(bsd + 16) = rb2;
        *(uint4*)(bsd + 24) = rb3;
        __syncthreads();
        if (kk + BK < MKPER) {
            aptr += BK; bptr += BK;
            ra0 = *(const uint4*)aptr;
            ra1 = *(const uint4*)(aptr + 32);
            rb0 = *(const uint4*)(bptr);
            rb1 = *(const uint4*)(bptr + 8);
            rb2 = *(const uint4*)(bptr + 16);
            rb3 = *(const uint4*)(bptr + 24);
        }
#pragma unroll
        for (int kb = 0; kb < 2; kb++) {
            bf16x8 af[2], bfr[4];
#pragma unroll
            for (int mt = 0; mt < 2; mt++)
                af[mt] = *(const bf16x8*)&As[(wr * 32 + mt * 16 + lm) * 72 + (kb * 4 + lg) * 8];
#pragma unroll
            for (int nt = 0; nt < 4; nt++)
                bfr[nt] = *(const bf16x8*)&Bs[(wc2 * 64 + nt * 16 + lm) * 72 + (kb * 4 + lg) * 8];
#pragma unroll
            for (int mt = 0; mt < 2; mt++)
#pragma unroll
                for (int nt = 0; nt < 4; nt++)
                    acc[mt][nt] = __builtin_amdgcn_mfma_f32_16x16x32_bf16(af[mt], bfr[nt], acc[mt][nt], 0, 0, 0);
        }
    }
#pragma unroll
    for (int mt = 0; mt < 2; mt++) {
        int rl0 = wr * 32 + mt * 16 + lg * 4;
#pragma unroll
        for (int nt = 0; nt < 4; nt++) {
            int col = wc2 * 64 + nt * 16 + lm;
#pragma unroll
            for (int r = 0; r < 4; r++) {
                int rloc = rl0 + r;
                float v = acc[mt][nt][r];
                if (e < 8) {
                    if (tile * 64 + rloc < n_rows) {
                        unsigned int entry = rowid_s[rloc];
                        unsigned int grow = entry & 0xFFFFu;
                        unsigned int slot = entry >> 16;
                        float g = gates[grow * 8 + e];
                        float bias = (split == 0) ? be[e * 128 + col] : 0.f;
                        float val = g * (v + bias);
                        if (pflag)
                            comb_part[((size_t)(split * 2 + slot) * B_ + grow) * 128 + col] = val;
                        else
                            atomicAdd(&comb_part[(size_t)grow * 128 + col], val);
                    }
                } else {
                    int row = tile * 64 + rloc;
                    if (pflag)
                        gen_part[((size_t)split * B_ + row) * 128 + col] = v;
                    else
                        atomicAdd(&gen_part[(size_t)row * 128 + col], v);
                }
            }
        }
    }
}

// ---------------- finalize ----------------
__global__ __launch_bounds__(256) void k_final(const float* __restrict__ gen_part,
                                               const float* __restrict__ comb_part,
                                               const float* __restrict__ bgen,
                                               float* __restrict__ out, int pflag) {
    int i = blockIdx.x * 256 + threadIdx.x;
    float c = 0.f, g = 0.f;
    if (pflag) {
#pragma unroll
        for (int p = 0; p < 16; p++) c += comb_part[(size_t)p * B_ * 128 + i];
#pragma unroll
        for (int p = 0; p < 8; p++) g += gen_part[(size_t)p * B_ * 128 + i];
    } else {
        c = comb_part[i];
        g = gen_part[i];
    }
    unsigned short cb = f2bf(c);
    float cf = __uint_as_float(((unsigned int)cb) << 16);
    out[i] = g + bgen[i & 127] + cf;
}

extern "C" void kernel_launch(void* const* d_in, const int* in_sizes, int n_in,
                              void* d_out, int out_size, void* d_ws, size_t ws_size,
                              hipStream_t stream) {
    (void)in_sizes; (void)n_in; (void)out_size;
    const float* ccd  = (const float*)d_in[0];
    const float* cyc  = (const float*)d_in[1];
    const float* dkp  = (const float*)d_in[2];
    const float* Wg1  = (const float*)d_in[3];
    const float* bg1  = (const float*)d_in[4];
    const float* Wg2  = (const float*)d_in[5];
    const float* bg2  = (const float*)d_in[6];
    const float* We   = (const float*)d_in[7];
    const float* be   = (const float*)d_in[8];
    const float* Wgen = (const float*)d_in[9];
    const float* bgen = (const float*)d_in[10];
    float* out = (float*)d_out;

    const size_t szA2   = (size_t)B_ * A2S_ * 2;       // 111.1 MB
    const size_t szXfb  = (size_t)B_ * F_ * 2;         // 52.4 MB
    const size_t szWeT  = (size_t)E_ * 128 * F_ * 2;   // 26.2 MB
    const size_t szWgT  = (size_t)128 * F_ * 2;        // 3.3 MB
    const size_t szBgT  = (size_t)512 * A2S_ * 2;      // 27.8 MB
    const size_t szGates = (size_t)B_ * 8 * 4;
    const size_t szRows  = (size_t)8 * 2048 * 4;
    const size_t szHp16  = (size_t)16 * B_ * 256 * 4;  // 33.6 MB
    const size_t szMoeP  = (size_t)24 * B_ * 128 * 4;  // 25.2 MB

    char* ws = (char*)d_ws;
    // mode 2: MFMA gate1; mode 1: fp32 gate1 w/ partials; mode 0: fp32 gate1 atomics
    size_t need2 = szA2 + szWeT + szWgT + szBgT + szGates + 256 + szRows + szHp16;
    size_t need1 = szXfb + szWeT + szWgT + szGates + 256 + szRows + szHp16;
    int mode = (ws_size >= need2) ? 2 : (ws_size >= need1 ? 1 : 0);

    size_t o = 0;
    unsigned short* A2 = nullptr; unsigned short* xfb = nullptr; unsigned short* BgT = nullptr;
    if (mode == 2) { A2 = (unsigned short*)(ws + o); o += szA2; }
    else           { xfb = (unsigned short*)(ws + o); o += szXfb; }
    unsigned short* WeT   = (unsigned short*)(ws + o); o += szWeT;
    unsigned short* WgenT = (unsigned short*)(ws + o); o += szWgT;
    if (mode == 2) { BgT = (unsigned short*)(ws + o); o += szBgT; }
    float* gates = (float*)(ws + o); o += szGates;
    unsigned int* cnt = (unsigned int*)(ws + o); o += 256;
    unsigned int* rows = (unsigned int*)(ws + o); o += szRows;
    char* R = ws + o;
    float* h_part    = (float*)R;
    float* comb_part = (float*)R;
    float* gen_part  = (float*)(R + (size_t)16 * B_ * 128 * 4);
    int nparts, pflag;
    if (mode >= 1) { nparts = 16; pflag = 1; }
    else {
        nparts = 1; pflag = 0;
        comb_part = (float*)(R + (size_t)B_ * 256 * 4);   // after atomic h_part
        gen_part  = comb_part + (size_t)B_ * 128;
    }
    (void)szMoeP;

    hipMemsetAsync(cnt, 0, 32, stream);
    if (mode == 0) {
        hipMemsetAsync(h_part, 0, (size_t)B_ * 256 * 4, stream);
        hipMemsetAsync(comb_part, 0, (size_t)B_ * 128 * 4, stream);
        hipMemsetAsync(gen_part,  0, (size_t)B_ * 128 * 4, stream);
    }

    k_transpose_bf16<<<dim3(F_ / 32, 4, 9), dim3(32, 8, 1), 0, stream>>>(We, Wgen, WeT, WgenT);

    const unsigned short* xrows; int astride;
    if (mode == 2) {
        k_build_a2<<<(B_ * 3392) / 256, 256, 0, stream>>>(dkp, ccd, A2);
        k_build_bgt<<<dim3(HK_ / 32, 8), dim3(32, 8), 0, stream>>>(Wg1, BgT);
        k_gate1_mfma<<<dim3(B_ / 64, 16), 256, 0, stream>>>(A2, BgT, h_part);
        xrows = A2 + DLLM_; astride = A2S_;
    } else {
        k_convert<<<(B_ * F_ / 4) / 256, 256, 0, stream>>>(ccd, xfb, B_ * F_ / 4);
        k_gate1_f32<<<dim3(16, 16), 256, 0, stream>>>(dkp, ccd, Wg1, h_part, nparts);
        xrows = xfb; astride = F_;
    }
    k_gate2<<<B_ / 8, 256, 0, stream>>>(h_part, cyc, Wg1, bg1, Wg2, bg2, gates, cnt, rows, nparts);
    k_moe<<<dim3(32, 9, MKSPLIT), 256, 0, stream>>>(xrows, astride, WeT, WgenT, be, gates, cnt, rows,
                                                    comb_part, gen_part, pflag);
    k_final<<<(B_ * 128) / 256, 256, 0, stream>>>(gen_part, comb_part, bgen, out, pflag);
}